// Round 12
// baseline (1474.176 us; speedup 1.0000x reference)
//
// Round 12: classic double-buffer on round-10 base (best: 1442us).
// Per iter: STAGE(t+1)->buf[(t+1)&1]; vmcnt(6) retires stage(t) (issued a
// full iter ago -> latency hidden); barrier; ds_read buf[t&1]+MFMA with
// compiler-scheduled lgkm (NO lgkmcnt(0) pin -- round-11's mistake); barrier.
// WAR safe: buf[(t+1)&1]'s readers finished before prev end-barrier.
#include <hip/hip_runtime.h>
#include <hip/hip_bf16.h>
#include <stdint.h>

#define NN 5000
#define NE 80000
#define NG 64
#define LAT 128
#define HIDN 512

typedef __hip_bfloat16 bf16;
typedef short short8 __attribute__((ext_vector_type(8)));
typedef float f32x4 __attribute__((ext_vector_type(4)));

__device__ __forceinline__ float b2f(bf16 v) { return __bfloat162float(v); }
__device__ __forceinline__ bf16 f2b(float v) { return __float2bfloat16(v); }
__device__ __forceinline__ short f2bs(float v) {
    bf16 b = __float2bfloat16(v);
    short s; __builtin_memcpy(&s, &b, 2); return s;
}

// ==================== K=512 GEMM, 128x64 tile, BK=64, classic dbuf ==========
// MODE: 0 plain A[M][512]; 1 gathered concat A (edge L1).
// LDS swizzle: phys = p ^ ((p>>3)&0x70).
template<int MODE>
__global__ __launch_bounds__(256, 4)
void gemm64_kernel(const bf16* __restrict__ A, const bf16* __restrict__ Bt,
                   const float* __restrict__ bias,
                   const float* residf, const bf16* residb,
                   float* out_sf, bf16* out_sb, bf16* out_rb,
                   int M, int N, int nnt,
                   const int* __restrict__ g_src, const int* __restrict__ g_dst,
                   const int* __restrict__ g_eb,
                   const bf16* __restrict__ g_ex, const bf16* __restrict__ g_ee,
                   const bf16* __restrict__ g_us)
{
    constexpr int K = 512, NT = K / 64;
    __shared__ __align__(16) char lds[49152];   // buf{0,1}: A 16KB + B 8KB each

    const int tid  = threadIdx.x;
    const int lane = tid & 63;
    const int w    = tid >> 6;
    const int li   = lane & 15, grp = lane >> 4;
    const int wr   = w >> 1, wc = w & 1;        // wave: 64x32 sub-tile

    const int nb  = gridDim.x;
    const int q   = nb >> 3, r = nb & 7;
    const int xcd = blockIdx.x & 7, jj = blockIdx.x >> 3;
    const int wg  = (xcd < r ? xcd * (q + 1) : r * (q + 1) + (xcd - r) * q) + jj;
    const int m0  = (wg / nnt) * 128;
    const int n0  = (wg % nnt) * 64;

    f32x4 acc[4][2];
#pragma unroll
    for (int m = 0; m < 4; ++m)
#pragma unroll
        for (int n = 0; n < 2; ++n)
            acc[m][n] = (f32x4){0.f, 0.f, 0.f, 0.f};

    // hoisted gather indices (MODE 1): 4 A-staging rows per thread
    int he[4], hs[4], hd[4], hb[4];
    if (MODE == 1) {
#pragma unroll
        for (int c = 0; c < 4; ++c) {
            const int p  = (tid + c * 256) * 16;
            const int qb = p ^ ((p >> 3) & 0x70);
            int e = m0 + (qb >> 7); if (e >= M) e = M - 1;
            he[c] = e;
            hs[c] = g_src[e]; hd[c] = g_dst[e]; hb[c] = g_eb[e];
        }
    }

    // stage K-tile t into buf[t&1]: A 4 loads + B 2 loads per thread
    auto STAGE = [&](int t) {
        if (t >= NT) return;
        char* base = lds + (t & 1) * 24576;
#pragma unroll
        for (int c = 0; c < 4; ++c) {
            const int p  = (tid + c * 256) * 16;
            const int qb = p ^ ((p >> 3) & 0x70);
            const int row = qb >> 7;
            const int kk  = (qb & 127) >> 1;
            const bf16* srcp;
            if (MODE == 1) {
                const int seg = t >> 1;
                const int so  = ((t & 1) << 6) + kk;
                if (seg == 0)      srcp = g_ex + (size_t)hs[c] * LAT + so;
                else if (seg == 1) srcp = g_ex + (size_t)hd[c] * LAT + so;
                else if (seg == 2) srcp = g_ee + (size_t)he[c] * LAT + so;
                else               srcp = g_us + (size_t)hb[c] * LAT + so;
            } else {
                int rr = m0 + row; if (rr >= M) rr = M - 1;
                srcp = A + (size_t)rr * K + t * 64 + kk;
            }
            __builtin_amdgcn_global_load_lds(
                (__attribute__((address_space(1))) const void*)srcp,
                (__attribute__((address_space(3))) void*)(base + p), 16, 0, 0);
        }
#pragma unroll
        for (int c = 0; c < 2; ++c) {
            const int p  = (tid + c * 256) * 16;
            const int qb = p ^ ((p >> 3) & 0x70);
            const int row = qb >> 7;                    // 0..63
            const int kk  = (qb & 127) >> 1;
            const bf16* srcp = Bt + (size_t)(n0 + row) * K + t * 64 + kk;
            __builtin_amdgcn_global_load_lds(
                (__attribute__((address_space(1))) const void*)srcp,
                (__attribute__((address_space(3))) void*)(base + 16384 + p), 16, 0, 0);
        }
    };

    STAGE(0);

    for (int t = 0; t < NT; ++t) {
        // issue next tile into the other buffer (its readers finished before
        // the previous end-barrier), then retire tile t (counted, not 0).
        STAGE(t + 1);
        if (t + 1 < NT) asm volatile("s_waitcnt vmcnt(6)" ::: "memory");
        else            asm volatile("s_waitcnt vmcnt(0)" ::: "memory");
        __builtin_amdgcn_s_barrier();

        const char* ldsA = lds + (t & 1) * 24576;
        const char* ldsB = ldsA + 16384;
        short8 af[4][2], bf[2][2];
#pragma unroll
        for (int m = 0; m < 4; ++m) {
            const int row = wr * 64 + m * 16 + li;
            const int xr  = (row & 7) << 4;
#pragma unroll
            for (int s = 0; s < 2; ++s)
                af[m][s] = *(const short8*)(ldsA +
                    ((row * 128 + s * 64 + grp * 16) ^ xr));
        }
#pragma unroll
        for (int n = 0; n < 2; ++n) {
            const int row = wc * 32 + n * 16 + li;
            const int xr  = (row & 7) << 4;
#pragma unroll
            for (int s = 0; s < 2; ++s)
                bf[n][s] = *(const short8*)(ldsB +
                    ((row * 128 + s * 64 + grp * 16) ^ xr));
        }
        __builtin_amdgcn_s_setprio(1);
#pragma unroll
        for (int m = 0; m < 4; ++m)
#pragma unroll
            for (int n = 0; n < 2; ++n)
#pragma unroll
                for (int s = 0; s < 2; ++s)
                    acc[m][n] = __builtin_amdgcn_mfma_f32_16x16x32_bf16(
                        af[m][s], bf[n][s], acc[m][n], 0, 0, 0);
        __builtin_amdgcn_s_setprio(0);
        // all our ds_reads of buf[t&1] were consumed by MFMA (lgkm waits) ->
        // reaching this barrier means every wave is done reading buf[t&1].
        __builtin_amdgcn_s_barrier();
    }

    // ---- epilogue (C/D layout: col=lane&15, row=(lane>>4)*4+j)
#pragma unroll
    for (int m = 0; m < 4; ++m) {
        const int growb = m0 + wr * 64 + m * 16 + grp * 4;
#pragma unroll
        for (int n = 0; n < 2; ++n) {
            const int gcol = n0 + wc * 32 + n * 16 + li;
            const float bv = bias[gcol];
#pragma unroll
            for (int j = 0; j < 4; ++j) {
                const int grow = growb + j;
                if (grow >= M) continue;
                float val = fmaxf(acc[m][n][j] + bv, 0.f);
                const size_t oo = (size_t)grow * N + gcol;
                if (out_rb) out_rb[oo] = f2b(val);
                float sum = val;
                if (residf) sum += residf[oo];
                if (residb) sum += b2f(residb[oo]);
                if (out_sf) out_sf[oo] = sum;
                if (out_sb) out_sb[oo] = f2b(sum);
            }
        }
    }
}

// ============================ 128x128 GEMM, BK=32 ===========================
// MODE: 0 plain, 2 POSA (K=128), 3 DISA (K=128)
template<int K, int MODE>
__global__ __launch_bounds__(256)
void gemm_kernel(const bf16* __restrict__ A,
                 const bf16* __restrict__ Bt,
                 const float* __restrict__ bias,
                 const float* residf, const bf16* residb,
                 float* out_sf, bf16* out_sb, bf16* out_rb,
                 int M, int N, int nnt,
                 const int* __restrict__ g_src, const int* __restrict__ g_dst,
                 const float* __restrict__ lp,
                 const float* __restrict__ aW, const float* __restrict__ ab)
{
    constexpr bool HASA = (MODE == 0);
    __shared__ __align__(16) bf16 As[HASA ? 128 * 32 : 8];
    __shared__ __align__(16) bf16 Bs[128 * 32];
    const int tid  = threadIdx.x;
    const int lane = tid & 63;
    const int w    = tid >> 6;
    const int li   = lane & 15, grp = lane >> 4;
    const int wr   = w >> 1, wc = w & 1;

    const int nb  = gridDim.x;
    const int q   = nb >> 3, r = nb & 7;
    const int xcd = blockIdx.x & 7, jj = blockIdx.x >> 3;
    const int wg  = (xcd < r ? xcd * (q + 1) : r * (q + 1) + (xcd - r) * q) + jj;
    const int m0  = (wg / nnt) * 128;
    const int n0  = (wg % nnt) * 128;

    f32x4 acc[4][4];
#pragma unroll
    for (int m = 0; m < 4; ++m)
#pragma unroll
        for (int n = 0; n < 4; ++n)
            acc[m][n] = (f32x4){0.f, 0.f, 0.f, 0.f};

    float r0[4], r1[4], r2[4];
    if (MODE == 2) {
#pragma unroll
        for (int m = 0; m < 4; ++m) {
            int rr = m0 + wr * 64 + m * 16 + li; if (rr >= M) rr = M - 1;
            r0[m] = lp[rr * 3 + 0]; r1[m] = lp[rr * 3 + 1]; r2[m] = lp[rr * 3 + 2];
        }
    } else if (MODE == 3) {
#pragma unroll
        for (int m = 0; m < 4; ++m) {
            int rr = m0 + wr * 64 + m * 16 + li; if (rr >= M) rr = M - 1;
            const int s = g_src[rr], d = g_dst[rr];
            const float dx = lp[s*3+0] - lp[d*3+0];
            const float dy = lp[s*3+1] - lp[d*3+1];
            const float dz = lp[s*3+2] - lp[d*3+2];
            r0[m] = sqrtf(dx*dx + dy*dy + dz*dz);
        }
    }

    const int offBase = w * 1024 + lane * 16;

    for (int kt = 0; kt < K / 32; ++kt) {
        if (HASA) {
#pragma unroll
            for (int c = 0; c < 2; ++c) {
                const int off = offBase + c * 4096;
                const int rr_ = off >> 6;
                const int g   = (off >> 4) & 3;
                const int gl  = g ^ ((rr_ >> 1) & 3);
                int rr = m0 + rr_; if (rr >= M) rr = M - 1;
                const bf16* srcp = A + (size_t)rr * K + kt * 32 + gl * 8;
                __builtin_amdgcn_global_load_lds(
                    (__attribute__((address_space(1))) const void*)srcp,
                    (__attribute__((address_space(3))) void*)((char*)As + off),
                    16, 0, 0);
            }
        }
#pragma unroll
        for (int c = 0; c < 2; ++c) {
            const int off = offBase + c * 4096;
            const int rr_ = off >> 6;
            const int g   = (off >> 4) & 3;
            const int gl  = g ^ ((rr_ >> 1) & 3);
            const bf16* srcp = Bt + (size_t)(n0 + rr_) * K + kt * 32 + gl * 8;
            __builtin_amdgcn_global_load_lds(
                (__attribute__((address_space(1))) const void*)srcp,
                (__attribute__((address_space(3))) void*)((char*)Bs + off),
                16, 0, 0);
        }
        __syncthreads();

        short8 af[4], bfr[4];
        if (HASA) {
#pragma unroll
            for (int m = 0; m < 4; ++m) {
                const int rr_  = wr * 64 + m * 16 + li;
                const int boff = rr_ * 64 + ((grp * 16) ^ (((rr_ >> 1) & 3) << 4));
                af[m] = *(const short8*)((const char*)As + boff);
            }
        } else {
            const int kk0 = kt * 32 + grp * 8;
            float bb[8], w0[8], w1[8], w2[8];
            *(f32x4*)&bb[0] = *(const f32x4*)(ab + kk0);
            *(f32x4*)&bb[4] = *(const f32x4*)(ab + kk0 + 4);
            *(f32x4*)&w0[0] = *(const f32x4*)(aW + kk0);
            *(f32x4*)&w0[4] = *(const f32x4*)(aW + kk0 + 4);
            if (MODE == 2) {
                *(f32x4*)&w1[0] = *(const f32x4*)(aW + K + kk0);
                *(f32x4*)&w1[4] = *(const f32x4*)(aW + K + kk0 + 4);
                *(f32x4*)&w2[0] = *(const f32x4*)(aW + 2 * K + kk0);
                *(f32x4*)&w2[4] = *(const f32x4*)(aW + 2 * K + kk0 + 4);
            }
#pragma unroll
            for (int m = 0; m < 4; ++m) {
                short8 v;
#pragma unroll
                for (int e = 0; e < 8; ++e) {
                    float s;
                    if (MODE == 2)
                        s = bb[e] + r0[m]*w0[e] + r1[m]*w1[e] + r2[m]*w2[e];
                    else
                        s = bb[e] + r0[m]*w0[e];
                    v[e] = f2bs(fmaxf(s, 0.f));
                }
                af[m] = v;
            }
        }
#pragma unroll
        for (int n = 0; n < 4; ++n) {
            const int rr_  = wc * 64 + n * 16 + li;
            const int boff = rr_ * 64 + ((grp * 16) ^ (((rr_ >> 1) & 3) << 4));
            bfr[n] = *(const short8*)((const char*)Bs + boff);
        }
#pragma unroll
        for (int m = 0; m < 4; ++m)
#pragma unroll
            for (int n = 0; n < 4; ++n)
                acc[m][n] = __builtin_amdgcn_mfma_f32_16x16x32_bf16(
                    af[m], bfr[n], acc[m][n], 0, 0, 0);
        __syncthreads();
    }

#pragma unroll
    for (int m = 0; m < 4; ++m) {
        const int growb = m0 + wr * 64 + m * 16 + grp * 4;
#pragma unroll
        for (int n = 0; n < 4; ++n) {
            const int gcol = n0 + wc * 64 + n * 16 + li;
            const float bv = bias[gcol];
#pragma unroll
            for (int j = 0; j < 4; ++j) {
                const int grow = growb + j;
                if (grow >= M) continue;
                float val = fmaxf(acc[m][n][j] + bv, 0.f);
                const size_t oo = (size_t)grow * N + gcol;
                if (out_rb) out_rb[oo] = f2b(val);
                float sum = val;
                if (residf) sum += residf[oo];
                if (residb) sum += b2f(residb[oo]);
                if (out_sf) out_sf[oo] = sum;
                if (out_sb) out_sb[oo] = f2b(sum);
            }
        }
    }
}

// ------------------------------------------------------ weight transpose ----
struct TDesc { const float* src; bf16* dst; int K, N, nblk, nb32; };
struct TPack { TDesc d[28]; int n; };

__global__ __launch_bounds__(256)
void transpose_kernel(TPack p)
{
    __shared__ float t[32][33];
    int b = blockIdx.x, mi = 0;
    while (mi < p.n && b >= p.d[mi].nblk) { b -= p.d[mi].nblk; ++mi; }
    if (mi >= p.n) return;
    TDesc d = p.d[mi];
    const int kb = b / d.nb32, nb = b % d.nb32;
    const int k0 = kb * 32, n0 = nb * 32;
    const int tx = threadIdx.x & 31, ty = threadIdx.x >> 5;
#pragma unroll
    for (int qq = 0; qq < 4; ++qq) {
        const int kk = ty + qq * 8;
        t[kk][tx] = d.src[(size_t)(k0 + kk) * d.N + n0 + tx];
    }
    __syncthreads();
#pragma unroll
    for (int qq = 0; qq < 4; ++qq) {
        const int nn = ty + qq * 8;
        d.dst[(size_t)(n0 + nn) * d.K + k0 + tx] = f2b(t[tx][nn]);
    }
}

// ---------------------------------------------------------------- CSR build
__global__ void deg_kernel(const int* __restrict__ idx, int n, int* deg)
{
    int e = blockIdx.x * 256 + threadIdx.x;
    if (e < n) atomicAdd(&deg[idx[e]], 1);
}

__global__ __launch_bounds__(256)
void scan_kernel(const int* __restrict__ deg, int* __restrict__ offs, int n)
{
    __shared__ int tot[256];
    const int t = threadIdx.x;
    const int per = (n + 255) / 256;
    const int b = t * per;
    int s = 0;
    for (int i = 0; i < per; ++i) if (b + i < n) s += deg[b + i];
    tot[t] = s;
    __syncthreads();
    for (int d = 1; d < 256; d <<= 1) {
        int v = (t >= d) ? tot[t - d] : 0;
        __syncthreads();
        tot[t] += v;
        __syncthreads();
    }
    int excl = (t == 0) ? 0 : tot[t - 1];
    for (int i = 0; i < per; ++i)
        if (b + i < n) { offs[b + i] = excl; excl += deg[b + i]; }
    if (t == 255) offs[n] = tot[255];
}

__global__ void perm_kernel(const int* __restrict__ idx, int n,
                            int* cursor, int* __restrict__ perm)
{
    int e = blockIdx.x * 256 + threadIdx.x;
    if (e < n) { int p = atomicAdd(&cursor[idx[e]], 1); perm[p] = e; }
}

// -------------------------------------------- node_in gather (CSR, no atomics)
__global__ __launch_bounds__(128)
void node_in_kernel(const bf16* __restrict__ exb, const bf16* __restrict__ e1f,
                    const bf16* __restrict__ usb, const int* __restrict__ nbat,
                    const int* __restrict__ offs_s, const int* __restrict__ perm_s,
                    const int* __restrict__ offs_d, const int* __restrict__ perm_d,
                    bf16* __restrict__ node_in)
{
    const int i = blockIdx.x;
    const int c = threadIdx.x;
    float s1 = 0.f, s2 = 0.f;
    const int s_lo = offs_s[i], s_hi = offs_s[i + 1];
    for (int j = s_lo; j < s_hi; ++j)
        s1 += b2f(e1f[(size_t)perm_s[j] * LAT + c]);
    const int d_lo = offs_d[i], d_hi = offs_d[i + 1];
    for (int j = d_lo; j < d_hi; ++j)
        s2 += b2f(e1f[(size_t)perm_d[j] * LAT + c]);
    const size_t o = (size_t)i * (4 * LAT);
    node_in[o + c]           = exb[(size_t)i * LAT + c];
    node_in[o + LAT + c]     = f2b(s1);
    node_in[o + 2 * LAT + c] = f2b(s2);
    node_in[o + 3 * LAT + c] = usb[(size_t)nbat[i] * LAT + c];
}

// -------------------------------- sorted-batch segmented reduce (few atomics)
__global__ __launch_bounds__(128)
void seg_reduce_kernel(const bf16* __restrict__ vals, const int* __restrict__ batch,
                       float* out, int R, int rows_per_block)
{
    const int r0 = blockIdx.x * rows_per_block;
    if (r0 >= R) return;
    const int c = threadIdx.x;
    const int r1 = min(r0 + rows_per_block, R);
    int g = batch[r0];
    float s = 0.f;
    for (int r = r0; r < r1; ++r) {
        const int gb = batch[r];
        if (gb != g) {
            atomicAdd(&out[(size_t)g * LAT + c], s);
            g = gb; s = 0.f;
        }
        s += b2f(vals[(size_t)r * LAT + c]);
    }
    atomicAdd(&out[(size_t)g * LAT + c], s);
}

// ------------------------------------------------------------ small kernels
__global__ void build_g_in_kernel(const float* __restrict__ us,
                                  const float* __restrict__ gx,
                                  const float* __restrict__ ge,
                                  bf16* __restrict__ out)
{
    int id = blockIdx.x * 256 + threadIdx.x;
    if (id >= NG * 384) return;
    int g = id / 384, c = id % 384;
    int seg = c >> 7, c7 = c & 127;
    float v;
    if (seg == 0)      v = us[g * LAT + c7];
    else if (seg == 1) v = gx[g * LAT + c7];
    else               v = ge[g * LAT + c7];
    out[id] = f2b(v);
}

__global__ void counts_kernel(const int* __restrict__ nbat, float* counts)
{
    int id = blockIdx.x * 256 + threadIdx.x;
    if (id < NN) atomicAdd(&counts[nbat[id]], 1.0f);
}

__global__ void cvt_kernel(const float* __restrict__ in, bf16* __restrict__ out, int n)
{
    int id = blockIdx.x * 256 + threadIdx.x;
    if (id < n) out[id] = f2b(in[id]);
}

__global__ void us_double_kernel(float* us)
{
    int id = blockIdx.x * 256 + threadIdx.x;
    if (id < NG * LAT) us[id] *= 2.0f;
}

__global__ __launch_bounds__(64)
void dec2_kernel(const bf16* __restrict__ dh, const float* __restrict__ W2,
                 const float* __restrict__ b2, const float* __restrict__ lp,
                 const int* __restrict__ nbat, float* __restrict__ ptmp, float* psum)
{
    int i = blockIdx.x;
    int l = threadIdx.x;
    float a0 = 0.f, a1 = 0.f, a2 = 0.f;
#pragma unroll
    for (int q = 0; q < 2; ++q) {
        int k = l + q * 64;
        float h = b2f(dh[i * LAT + k]);
        a0 += h * W2[k * 3 + 0];
        a1 += h * W2[k * 3 + 1];
        a2 += h * W2[k * 3 + 2];
    }
#pragma unroll
    for (int off = 32; off > 0; off >>= 1) {
        a0 += __shfl_down(a0, off, 64);
        a1 += __shfl_down(a1, off, 64);
        a2 += __shfl_down(a2, off, 64);
    }
    if (l == 0) {
        int g = nbat[i];
        float p0 = lp[i*3+0] + a0 + b2[0];
        float p1 = lp[i*3+1] + a1 + b2[1];
        float p2 = lp[i*3+2] + a2 + b2[2];
        ptmp[i*3+0] = p0; ptmp[i*3+1] = p1; ptmp[i*3+2] = p2;
        atomicAdd(&psum[g*3+0], p0);
        atomicAdd(&psum[g*3+1], p1);
        atomicAdd(&psum[g*3+2], p2);
    }
}

__global__ void finalize_pos_kernel(const float* __restrict__ ptmp,
                                    const float* __restrict__ psum,
                                    const float* __restrict__ counts,
                                    const int* __restrict__ nbat,
                                    float* __restrict__ lp, float* __restrict__ pos_out)
{
    int id = blockIdx.x * 256 + threadIdx.x;
    if (id >= NN * 3) return;
    int i = id / 3, d = id % 3;
    int g = nbat[i];
    float v = ptmp[id] - psum[g*3+d] / fmaxf(counts[g], 1.f);
    lp[id] = v;
    pos_out[id] = v;
}

// ----------------------------------------------------------------- launch ----
extern "C" void kernel_launch(void* const* d_in, const int* in_sizes, int n_in,
                              void* d_out, int out_size, void* d_ws, size_t ws_size,
                              hipStream_t stream)
{
    const float* x        = (const float*)d_in[0];
    const int*   ei       = (const int*)d_in[1];
    const int*   src      = ei;
    const int*   dst      = ei + NE;
    const float* eattr    = (const float*)d_in[2];
    const float* u        = (const float*)d_in[3];
    const int*   nbat     = (const int*)d_in[4];
    const int*   ebat     = (const int*)d_in[5];
    const float* lp_init  = (const float*)d_in[7];
    const float* pW1 = (const float*)d_in[8];  const float* pb1 = (const float*)d_in[9];
    const float* pW2 = (const float*)d_in[10]; const float* pb2 = (const float*)d_in[11];
    const float* dW1 = (const float*)d_in[12]; const float* db1 = (const float*)d_in[13];
    const float* dW2 = (const float*)d_in[14]; const float* db2 = (const float*)d_in[15];
    const float* eW1 = (const float*)d_in[16]; const float* eb1 = (const float*)d_in[17];
    const float* eW2 = (const float*)d_in[18]; const float* eb2 = (const float*)d_in[19];
    const float* eW3 = (const float*)d_in[20]; const float* eb3 = (const float*)d_in[21];
    const float* nW1 = (const float*)d_in[22]; const float* nb1 = (const float*)d_in[23];
    const float* nW2 = (const float*)d_in[24]; const float* nb2 = (const float*)d_in[25];
    const float* nW3 = (const float*)d_in[26]; const float* nb3 = (const float*)d_in[27];
    const float* gW1 = (const float*)d_in[28]; const float* gb1 = (const float*)d_in[29];
    const float* gW2 = (const float*)d_in[30]; const float* gb2 = (const float*)d_in[31];
    const float* gW3 = (const float*)d_in[32]; const float* gb3 = (const float*)d_in[33];
    const float* dcW1 = (const float*)d_in[34]; const float* dcb1 = (const float*)d_in[35];
    const float* dcW2 = (const float*)d_in[36]; const float* dcb2 = (const float*)d_in[37];

    float* xs = (float*)d_out;
    float* es = xs + (size_t)NN * LAT;
    float* us = es + (size_t)NE * LAT;
    float* pos_out = us + (size_t)NG * LAT;

    char* wp = (char*)d_ws;
    auto alloc = [&](size_t nbytes) {
        void* r = (void*)wp;
        wp += (nbytes + 255) & ~(size_t)255;
        return r;
    };
    bf16* eW1t = (bf16*)alloc((size_t)3*512*512*2);
    bf16* eW2t = (bf16*)alloc((size_t)3*512*512*2);
    bf16* eW3t = (bf16*)alloc((size_t)3*128*512*2);
    bf16* nW1t = (bf16*)alloc((size_t)3*512*512*2);
    bf16* nW2t = (bf16*)alloc((size_t)3*512*512*2);
    bf16* nW3t = (bf16*)alloc((size_t)3*128*512*2);
    bf16* gW1t = (bf16*)alloc((size_t)2*512*384*2);
    bf16* gW2t = (bf16*)alloc((size_t)2*512*512*2);
    bf16* gW3t = (bf16*)alloc((size_t)2*128*512*2);
    bf16* pW2t = (bf16*)alloc((size_t)128*128*2);
    bf16* dW2t = (bf16*)alloc((size_t)128*128*2);
    bf16* dcW1t = (bf16*)alloc((size_t)128*128*2);
    bf16* exb  = (bf16*)alloc((size_t)NN*LAT*2);
    bf16* usb  = (bf16*)alloc((size_t)NG*LAT*2);
    bf16* esb  = (bf16*)alloc((size_t)NE*LAT*2);
    bf16* eeb  = (bf16*)alloc((size_t)NE*LAT*2);
    bf16* h1   = (bf16*)alloc((size_t)NE*HIDN*2);
    bf16* h2   = (bf16*)alloc((size_t)NE*HIDN*2);
    bf16* e1f  = (bf16*)alloc((size_t)NE*LAT*2);
    bf16* x1f  = (bf16*)alloc((size_t)NN*LAT*2);
    float* gx  = (float*)alloc((size_t)NG*LAT*4);
    float* ge  = (float*)alloc((size_t)NG*LAT*4);
    bf16* node_in = (bf16*)alloc((size_t)NN*HIDN*2);
    bf16* nh1  = (bf16*)alloc((size_t)NN*HIDN*2);
    bf16* nh2  = (bf16*)alloc((size_t)NN*HIDN*2);
    bf16* xsb  = (bf16*)alloc((size_t)NN*LAT*2);
    bf16* g_in = (bf16*)alloc((size_t)NG*384*2);
    bf16* gh1  = (bf16*)alloc((size_t)NG*HIDN*2);
    bf16* gh2  = (bf16*)alloc((size_t)NG*HIDN*2);
    bf16* dh   = (bf16*)alloc((size_t)NN*LAT*2);
    float* lp   = (float*)alloc((size_t)NN*3*4);
    float* ptmp = (float*)alloc((size_t)NN*3*4);
    float* psum = (float*)alloc((size_t)NG*3*4);
    float* counts = (float*)alloc((size_t)NG*4);
    int* deg    = (int*)alloc((size_t)NN*4);
    int* offs_s = (int*)alloc((size_t)(NN+1)*4);
    int* offs_d = (int*)alloc((size_t)(NN+1)*4);
    int* cur_s  = (int*)alloc((size_t)NN*4);
    int* cur_d  = (int*)alloc((size_t)NN*4);
    int* perm_s = (int*)alloc((size_t)NE*4);
    int* perm_d = (int*)alloc((size_t)NE*4);

    hipMemcpyAsync(xs, x,     (size_t)NN*LAT*4, hipMemcpyDeviceToDevice, stream);
    hipMemcpyAsync(us, u,     (size_t)NG*LAT*4, hipMemcpyDeviceToDevice, stream);
    hipMemcpyAsync(lp, lp_init, (size_t)NN*3*4, hipMemcpyDeviceToDevice, stream);
    hipMemsetAsync(counts, 0, NG*4, stream);
    counts_kernel<<<(NN+255)/256, 256, 0, stream>>>(nbat, counts);
    cvt_kernel<<<(NG*LAT+255)/256, 256, 0, stream>>>(us, usb, NG*LAT);
    cvt_kernel<<<(NE*LAT+255)/256, 256, 0, stream>>>(eattr, esb, NE*LAT);

    const int eb256 = (NE + 255) / 256;
    hipMemsetAsync(deg, 0, NN*4, stream);
    deg_kernel<<<eb256, 256, 0, stream>>>(src, NE, deg);
    scan_kernel<<<1, 256, 0, stream>>>(deg, offs_s, NN);
    hipMemsetAsync(deg, 0, NN*4, stream);
    deg_kernel<<<eb256, 256, 0, stream>>>(dst, NE, deg);
    scan_kernel<<<1, 256, 0, stream>>>(deg, offs_d, NN);
    hipMemcpyAsync(cur_s, offs_s, NN*4, hipMemcpyDeviceToDevice, stream);
    hipMemcpyAsync(cur_d, offs_d, NN*4, hipMemcpyDeviceToDevice, stream);
    perm_kernel<<<eb256, 256, 0, stream>>>(src, NE, cur_s, perm_s);
    perm_kernel<<<eb256, 256, 0, stream>>>(dst, NE, cur_d, perm_d);

    TPack pk{}; int nd = 0, totb = 0;
    auto addT = [&](const float* s, bf16* d, int K, int N) {
        pk.d[nd].src = s; pk.d[nd].dst = d; pk.d[nd].K = K; pk.d[nd].N = N;
        pk.d[nd].nblk = (K/32)*(N/32); pk.d[nd].nb32 = N/32;
        totb += pk.d[nd].nblk; ++nd;
    };
    for (int l = 0; l < 3; ++l) {
        addT(eW1 + (size_t)l*512*512, eW1t + (size_t)l*512*512, 512, 512);
        addT(eW2 + (size_t)l*512*512, eW2t + (size_t)l*512*512, 512, 512);
        addT(eW3 + (size_t)l*512*128, eW3t + (size_t)l*128*512, 512, 128);
        addT(nW1 + (size_t)l*512*512, nW1t + (size_t)l*512*512, 512, 512);
        addT(nW2 + (size_t)l*512*512, nW2t + (size_t)l*512*512, 512, 512);
        addT(nW3 + (size_t)l*512*128, nW3t + (size_t)l*128*512, 512, 128);
    }
    for (int l = 0; l < 2; ++l) {
        addT(gW1 + (size_t)l*384*512, gW1t + (size_t)l*512*384, 384, 512);
        addT(gW2 + (size_t)l*512*512, gW2t + (size_t)l*512*512, 512, 512);
        addT(gW3 + (size_t)l*512*128, gW3t + (size_t)l*128*512, 512, 128);
    }
    addT(pW2, pW2t, 128, 128);
    addT(dW2, dW2t, 128, 128);
    addT(dcW1, dcW1t, 128, 128);
    pk.n = nd;
    transpose_kernel<<<totb, 256, 0, stream>>>(pk);

    const int mtE  = NE / 128;             // 625
    const int mtN  = (NN + 127) / 128;     // 40
    #define NIL3 nullptr, nullptr, nullptr

    for (int l = 0; l < 3; ++l) {
        // ex = xs + relu(relu(lp@pW1+pb1)@pW2+pb2)  [POSA]
        gemm_kernel<128,2><<<mtN, 256, 0, stream>>>(
            nullptr, pW2t, pb2, xs, nullptr, nullptr, exb, nullptr, NN, LAT, 1,
            nullptr, nullptr, lp, pW1, pb1);
        // ee = es + relu(relu(len@dW1+db1)@dW2+db2)  [DISA]
        gemm_kernel<128,3><<<mtE, 256, 0, stream>>>(
            nullptr, dW2t, db2, nullptr, esb, nullptr, eeb, nullptr, NE, LAT, 1,
            src, dst, lp, dW1, db1);
        // edge MLP layer 1 (gathered concat input), 128x64 tile, dbuf
        gemm64_kernel<1><<<mtE*8, 256, 0, stream>>>(
            nullptr, eW1t + (size_t)l*512*512, eb1 + l*HIDN, nullptr, nullptr,
            nullptr, nullptr, h1, NE, HIDN, 8,
            src, dst, ebat, exb, eeb, usb);
        // edge MLP layer 2
        gemm64_kernel<0><<<mtE*8, 256, 0, stream>>>(
            h1, eW2t + (size_t)l*512*512, eb2 + l*HIDN, nullptr, nullptr,
            nullptr, nullptr, h2, NE, HIDN, 8, NIL3, NIL3);
        // edge MLP layer 3: e1 (bf16) ; esb += e1 ; es f32 at last layer
        gemm64_kernel<0><<<mtE*2, 256, 0, stream>>>(
            h2, eW3t + (size_t)l*128*512, eb3 + l*LAT, nullptr, esb,
            (l == 2 ? es : nullptr), (l < 2 ? esb : nullptr), e1f, NE, LAT, 2,
            NIL3, NIL3);
        if (l < 2) {
            hipMemsetAsync(gx, 0, (size_t)2*NG*LAT*4, stream);
            seg_reduce_kernel<<<(NE+63)/64, 128, 0, stream>>>(e1f, ebat, ge, NE, 64);
        }
        node_in_kernel<<<NN, 128, 0, stream>>>(
            exb, e1f, usb, nbat, offs_s, perm_s, offs_d, perm_d, node_in);
        gemm64_kernel<0><<<mtN*8, 256, 0, stream>>>(
            node_in, nW1t + (size_t)l*512*512, nb1 + l*HIDN, nullptr, nullptr,
            nullptr, nullptr, nh1, NN, HIDN, 8, NIL3, NIL3);
        gemm64_kernel<0><<<mtN*8, 256, 0, stream>>>(
            nh1, nW2t + (size_t)l*512*512, nb2 + l*HIDN, nullptr, nullptr,
            nullptr, nullptr, nh2, NN, HIDN, 8, NIL3, NIL3);
        gemm64_kernel<0><<<mtN*2, 256, 0, stream>>>(
            nh2, nW3t + (size_t)l*128*512, nb3 + l*LAT, xs, nullptr,
            xs, xsb, x1f, NN, LAT, 2, NIL3, NIL3);
        if (l < 2) {
            seg_reduce_kernel<<<(NN+31)/32, 128, 0, stream>>>(x1f, nbat, gx, NN, 32);
            build_g_in_kernel<<<(NG*384+255)/256, 256, 0, stream>>>(us, gx, ge, g_in);
            gemm_kernel<384,0><<<4, 256, 0, stream>>>(
                g_in, gW1t + (size_t)l*512*384, gb1 + l*HIDN, nullptr, nullptr,
                nullptr, nullptr, gh1, NG, HIDN, 4, NIL3, nullptr, nullptr);
            gemm_kernel<512,0><<<4, 256, 0, stream>>>(
                gh1, gW2t + (size_t)l*512*512, gb2 + l*HIDN, nullptr, nullptr,
                nullptr, nullptr, gh2, NG, HIDN, 4, NIL3, nullptr, nullptr);
            gemm_kernel<512,0><<<1, 256, 0, stream>>>(
                gh2, gW3t + (size_t)l*128*512, gb3 + l*LAT, us, nullptr,
                us, usb, nullptr, NG, LAT, 1, NIL3, nullptr, nullptr);
        } else {
            us_double_kernel<<<(NG*LAT+255)/256, 256, 0, stream>>>(us);
        }
        gemm_kernel<128,0><<<mtN, 256, 0, stream>>>(
            xsb, dcW1t, dcb1, nullptr, nullptr, nullptr, nullptr, dh, NN, LAT, 1,
            NIL3, nullptr, nullptr);
        hipMemsetAsync(psum, 0, NG*3*4, stream);
        dec2_kernel<<<NN, 64, 0, stream>>>(dh, dcW2, dcb2, lp, nbat, ptmp, psum);
        finalize_pos_kernel<<<(NN*3+255)/256, 256, 0, stream>>>(
            ptmp, psum, counts, nbat, lp, pos_out + (size_t)l*NN*3);
    }
    (void)in_sizes; (void)n_in; (void)out_size; (void)ws_size;
}

// Round 13
// 1269.814 us; speedup vs baseline: 1.1609x; 1.1609x over previous
//
// Round 13: revert gemm64 to round-10 (dbuf refuted: r11/r12 = 87us > r10 81us).
// + K=128 kernels get the r10 occupancy fix (128x64 tile, acc[4][2], lb(256,4))
// + POSA/DISA merged into one dispatch; node_in/seg_reduce merged.
#include <hip/hip_runtime.h>
#include <hip/hip_bf16.h>
#include <stdint.h>

#define NN 5000
#define NE 80000
#define NG 64
#define LAT 128
#define HIDN 512

typedef __hip_bfloat16 bf16;
typedef short short8 __attribute__((ext_vector_type(8)));
typedef float f32x4 __attribute__((ext_vector_type(4)));

__device__ __forceinline__ float b2f(bf16 v) { return __bfloat162float(v); }
__device__ __forceinline__ bf16 f2b(float v) { return __float2bfloat16(v); }
__device__ __forceinline__ short f2bs(float v) {
    bf16 b = __float2bfloat16(v);
    short s; __builtin_memcpy(&s, &b, 2); return s;
}

// ==================== K=512 GEMM, 128x64 tile, BK=64 (round-10) =============
template<int MODE>
__global__ __launch_bounds__(256, 4)
void gemm64_kernel(const bf16* __restrict__ A, const bf16* __restrict__ Bt,
                   const float* __restrict__ bias,
                   const float* residf, const bf16* residb,
                   float* out_sf, bf16* out_sb, bf16* out_rb,
                   int M, int N, int nnt,
                   const int* __restrict__ g_src, const int* __restrict__ g_dst,
                   const int* __restrict__ g_eb,
                   const bf16* __restrict__ g_ex, const bf16* __restrict__ g_ee,
                   const bf16* __restrict__ g_us)
{
    constexpr int K = 512, NT = K / 64;
    __shared__ __align__(16) char lds[24576];   // A @0 (16KB), B @16384 (8KB)

    const int tid  = threadIdx.x;
    const int lane = tid & 63;
    const int w    = tid >> 6;
    const int li   = lane & 15, grp = lane >> 4;
    const int wr   = w >> 1, wc = w & 1;

    const int nb  = gridDim.x;
    const int q   = nb >> 3, r = nb & 7;
    const int xcd = blockIdx.x & 7, jj = blockIdx.x >> 3;
    const int wg  = (xcd < r ? xcd * (q + 1) : r * (q + 1) + (xcd - r) * q) + jj;
    const int m0  = (wg / nnt) * 128;
    const int n0  = (wg % nnt) * 64;

    f32x4 acc[4][2];
#pragma unroll
    for (int m = 0; m < 4; ++m)
#pragma unroll
        for (int n = 0; n < 2; ++n)
            acc[m][n] = (f32x4){0.f, 0.f, 0.f, 0.f};

    int he[4], hs[4], hd[4], hb[4];
    if (MODE == 1) {
#pragma unroll
        for (int c = 0; c < 4; ++c) {
            const int p  = (tid + c * 256) * 16;
            const int qb = p ^ ((p >> 3) & 0x70);
            int e = m0 + (qb >> 7); if (e >= M) e = M - 1;
            he[c] = e;
            hs[c] = g_src[e]; hd[c] = g_dst[e]; hb[c] = g_eb[e];
        }
    }

    char* ldsA = lds;
    char* ldsB = lds + 16384;

    for (int t = 0; t < NT; ++t) {
#pragma unroll
        for (int c = 0; c < 4; ++c) {
            const int p  = (tid + c * 256) * 16;
            const int qb = p ^ ((p >> 3) & 0x70);
            const int row = qb >> 7;
            const int kk  = (qb & 127) >> 1;
            const bf16* srcp;
            if (MODE == 1) {
                const int seg = t >> 1;
                const int so  = ((t & 1) << 6) + kk;
                if (seg == 0)      srcp = g_ex + (size_t)hs[c] * LAT + so;
                else if (seg == 1) srcp = g_ex + (size_t)hd[c] * LAT + so;
                else if (seg == 2) srcp = g_ee + (size_t)he[c] * LAT + so;
                else               srcp = g_us + (size_t)hb[c] * LAT + so;
            } else {
                int rr = m0 + row; if (rr >= M) rr = M - 1;
                srcp = A + (size_t)rr * K + t * 64 + kk;
            }
            __builtin_amdgcn_global_load_lds(
                (__attribute__((address_space(1))) const void*)srcp,
                (__attribute__((address_space(3))) void*)(ldsA + p), 16, 0, 0);
        }
#pragma unroll
        for (int c = 0; c < 2; ++c) {
            const int p  = (tid + c * 256) * 16;
            const int qb = p ^ ((p >> 3) & 0x70);
            const int row = qb >> 7;
            const int kk  = (qb & 127) >> 1;
            const bf16* srcp = Bt + (size_t)(n0 + row) * K + t * 64 + kk;
            __builtin_amdgcn_global_load_lds(
                (__attribute__((address_space(1))) const void*)srcp,
                (__attribute__((address_space(3))) void*)(ldsB + p), 16, 0, 0);
        }
        __syncthreads();

        short8 af[4][2], bf[2][2];
#pragma unroll
        for (int m = 0; m < 4; ++m) {
            const int row = wr * 64 + m * 16 + li;
            const int xr  = (row & 7) << 4;
#pragma unroll
            for (int s = 0; s < 2; ++s)
                af[m][s] = *(const short8*)(ldsA +
                    ((row * 128 + s * 64 + grp * 16) ^ xr));
        }
#pragma unroll
        for (int n = 0; n < 2; ++n) {
            const int row = wc * 32 + n * 16 + li;
            const int xr  = (row & 7) << 4;
#pragma unroll
            for (int s = 0; s < 2; ++s)
                bf[n][s] = *(const short8*)(ldsB +
                    ((row * 128 + s * 64 + grp * 16) ^ xr));
        }
#pragma unroll
        for (int m = 0; m < 4; ++m)
#pragma unroll
            for (int n = 0; n < 2; ++n)
#pragma unroll
                for (int s = 0; s < 2; ++s)
                    acc[m][n] = __builtin_amdgcn_mfma_f32_16x16x32_bf16(
                        af[m][s], bf[n][s], acc[m][n], 0, 0, 0);
        __syncthreads();
    }

#pragma unroll
    for (int m = 0; m < 4; ++m) {
        const int growb = m0 + wr * 64 + m * 16 + grp * 4;
#pragma unroll
        for (int n = 0; n < 2; ++n) {
            const int gcol = n0 + wc * 32 + n * 16 + li;
            const float bv = bias[gcol];
#pragma unroll
            for (int j = 0; j < 4; ++j) {
                const int grow = growb + j;
                if (grow >= M) continue;
                float val = fmaxf(acc[m][n][j] + bv, 0.f);
                const size_t oo = (size_t)grow * N + gcol;
                if (out_rb) out_rb[oo] = f2b(val);
                float sum = val;
                if (residf) sum += residf[oo];
                if (residb) sum += b2f(residb[oo]);
                if (out_sf) out_sf[oo] = sum;
                if (out_sb) out_sb[oo] = f2b(sum);
            }
        }
    }
}

// ============== merged POSA+DISA kernel (K=128, 128x64 tile, BK=32) =========
// blocks [0,nP): POSA (exb = bf16(relu(posmlp)+xs))
// blocks [nP,..): DISA (eeb = bf16(relu(dismlp)+esb))
__global__ __launch_bounds__(256, 4)
void posdis_kernel(int nP,
                   const float* __restrict__ lp,
                   const int* __restrict__ src, const int* __restrict__ dst,
                   const bf16* __restrict__ pBt, const float* __restrict__ pb2v,
                   const float* __restrict__ pW1v, const float* __restrict__ pb1v,
                   const float* __restrict__ xs, bf16* __restrict__ exb,
                   const bf16* __restrict__ dBt, const float* __restrict__ db2v,
                   const float* __restrict__ dW1v, const float* __restrict__ db1v,
                   const bf16* __restrict__ esb, bf16* __restrict__ eeb)
{
    constexpr int K = 128;
    __shared__ __align__(16) bf16 Bs[64 * 32];   // 4KB
    const int tid  = threadIdx.x;
    const int lane = tid & 63;
    const int w    = tid >> 6;
    const int li   = lane & 15, grp = lane >> 4;
    const int wr   = w >> 1, wc = w & 1;

    const bool isP = (int)blockIdx.x < nP;
    const int bid  = isP ? blockIdx.x : blockIdx.x - nP;
    const int M    = isP ? NN : NE;
    const int m0   = (bid >> 1) * 128;
    const int n0   = (bid & 1) * 64;
    const bf16*  Bt   = isP ? pBt  : dBt;
    const float* bias = isP ? pb2v : db2v;
    const float* aW   = isP ? pW1v : dW1v;
    const float* ab   = isP ? pb1v : db1v;

    f32x4 acc[4][2];
#pragma unroll
    for (int m = 0; m < 4; ++m)
#pragma unroll
        for (int n = 0; n < 2; ++n)
            acc[m][n] = (f32x4){0.f, 0.f, 0.f, 0.f};

    float r0[4], r1[4], r2[4];
#pragma unroll
    for (int m = 0; m < 4; ++m) {
        int rr = m0 + wr * 64 + m * 16 + li; if (rr >= M) rr = M - 1;
        if (isP) {
            r0[m] = lp[rr * 3 + 0]; r1[m] = lp[rr * 3 + 1]; r2[m] = lp[rr * 3 + 2];
        } else {
            const int s = src[rr], d = dst[rr];
            const float dx = lp[s*3+0] - lp[d*3+0];
            const float dy = lp[s*3+1] - lp[d*3+1];
            const float dz = lp[s*3+2] - lp[d*3+2];
            r0[m] = sqrtf(dx*dx + dy*dy + dz*dz);
        }
    }

    for (int kt = 0; kt < K / 32; ++kt) {
        // stage B (64 rows x 32 k = 4KB), granule-swizzled
        {
            const int off = tid * 16;
            const int rr_ = off >> 6;
            const int g   = (off >> 4) & 3;
            const int gl  = g ^ ((rr_ >> 1) & 3);
            const bf16* srcp = Bt + (size_t)(n0 + rr_) * K + kt * 32 + gl * 8;
            __builtin_amdgcn_global_load_lds(
                (__attribute__((address_space(1))) const void*)srcp,
                (__attribute__((address_space(3))) void*)((char*)Bs + off),
                16, 0, 0);
        }
        __syncthreads();

        // A fragment in-register
        const int kk0 = kt * 32 + grp * 8;
        float bb[8], w0[8], w1[8], w2[8];
        *(f32x4*)&bb[0] = *(const f32x4*)(ab + kk0);
        *(f32x4*)&bb[4] = *(const f32x4*)(ab + kk0 + 4);
        *(f32x4*)&w0[0] = *(const f32x4*)(aW + kk0);
        *(f32x4*)&w0[4] = *(const f32x4*)(aW + kk0 + 4);
        if (isP) {
            *(f32x4*)&w1[0] = *(const f32x4*)(aW + K + kk0);
            *(f32x4*)&w1[4] = *(const f32x4*)(aW + K + kk0 + 4);
            *(f32x4*)&w2[0] = *(const f32x4*)(aW + 2 * K + kk0);
            *(f32x4*)&w2[4] = *(const f32x4*)(aW + 2 * K + kk0 + 4);
        }
        short8 af[4], bfr[2];
#pragma unroll
        for (int m = 0; m < 4; ++m) {
            short8 v;
#pragma unroll
            for (int e = 0; e < 8; ++e) {
                float s = isP ? (bb[e] + r0[m]*w0[e] + r1[m]*w1[e] + r2[m]*w2[e])
                              : (bb[e] + r0[m]*w0[e]);
                v[e] = f2bs(fmaxf(s, 0.f));
            }
            af[m] = v;
        }
#pragma unroll
        for (int n = 0; n < 2; ++n) {
            const int rr_  = wc * 32 + n * 16 + li;
            const int boff = rr_ * 64 + ((grp * 16) ^ (((rr_ >> 1) & 3) << 4));
            bfr[n] = *(const short8*)((const char*)Bs + boff);
        }
#pragma unroll
        for (int m = 0; m < 4; ++m)
#pragma unroll
            for (int n = 0; n < 2; ++n)
                acc[m][n] = __builtin_amdgcn_mfma_f32_16x16x32_bf16(
                    af[m], bfr[n], acc[m][n], 0, 0, 0);
        __syncthreads();
    }

#pragma unroll
    for (int m = 0; m < 4; ++m) {
        const int growb = m0 + wr * 64 + m * 16 + grp * 4;
#pragma unroll
        for (int n = 0; n < 2; ++n) {
            const int gcol = n0 + wc * 32 + n * 16 + li;
            const float bv = bias[gcol];
#pragma unroll
            for (int j = 0; j < 4; ++j) {
                const int grow = growb + j;
                if (grow >= M) continue;
                float val = fmaxf(acc[m][n][j] + bv, 0.f);
                const size_t oo = (size_t)grow * LAT + gcol;
                if (isP) exb[oo] = f2b(val + xs[oo]);
                else     eeb[oo] = f2b(val + b2f(esb[oo]));
            }
        }
    }
}

// ============= generic plain-A GEMM (128x64 tile, BK=32) =====================
// used by: decoder (K=128), global MLP (K=384/512, M=64)
template<int K>
__global__ __launch_bounds__(256, 4)
void gemm_kernel(const bf16* __restrict__ A,
                 const bf16* __restrict__ Bt,
                 const float* __restrict__ bias,
                 const float* residf,
                 float* out_sf, bf16* out_sb, bf16* out_rb,
                 int M, int N, int nnt)
{
    __shared__ __align__(16) bf16 As[128 * 32];  // 8KB
    __shared__ __align__(16) bf16 Bs[64 * 32];   // 4KB
    const int tid  = threadIdx.x;
    const int lane = tid & 63;
    const int w    = tid >> 6;
    const int li   = lane & 15, grp = lane >> 4;
    const int wr   = w >> 1, wc = w & 1;

    const int nb  = gridDim.x;
    const int q   = nb >> 3, r = nb & 7;
    const int xcd = blockIdx.x & 7, jj = blockIdx.x >> 3;
    const int wg  = (nb >= 8)
        ? (xcd < r ? xcd * (q + 1) : r * (q + 1) + (xcd - r) * q) + jj
        : (int)blockIdx.x;
    const int m0  = (wg / nnt) * 128;
    const int n0  = (wg % nnt) * 64;

    f32x4 acc[4][2];
#pragma unroll
    for (int m = 0; m < 4; ++m)
#pragma unroll
        for (int n = 0; n < 2; ++n)
            acc[m][n] = (f32x4){0.f, 0.f, 0.f, 0.f};

    for (int kt = 0; kt < K / 32; ++kt) {
#pragma unroll
        for (int c = 0; c < 2; ++c) {
            const int off = tid * 16 + c * 4096;
            const int rr_ = off >> 6;
            const int g   = (off >> 4) & 3;
            const int gl  = g ^ ((rr_ >> 1) & 3);
            int rr = m0 + rr_; if (rr >= M) rr = M - 1;
            const bf16* srcp = A + (size_t)rr * K + kt * 32 + gl * 8;
            __builtin_amdgcn_global_load_lds(
                (__attribute__((address_space(1))) const void*)srcp,
                (__attribute__((address_space(3))) void*)((char*)As + off),
                16, 0, 0);
        }
        {
            const int off = tid * 16;
            const int rr_ = off >> 6;
            const int g   = (off >> 4) & 3;
            const int gl  = g ^ ((rr_ >> 1) & 3);
            const bf16* srcp = Bt + (size_t)(n0 + rr_) * K + kt * 32 + gl * 8;
            __builtin_amdgcn_global_load_lds(
                (__attribute__((address_space(1))) const void*)srcp,
                (__attribute__((address_space(3))) void*)((char*)Bs + off),
                16, 0, 0);
        }
        __syncthreads();

        short8 af[4], bfr[2];
#pragma unroll
        for (int m = 0; m < 4; ++m) {
            const int rr_  = wr * 64 + m * 16 + li;
            const int boff = rr_ * 64 + ((grp * 16) ^ (((rr_ >> 1) & 3) << 4));
            af[m] = *(const short8*)((const char*)As + boff);
        }
#pragma unroll
        for (int n = 0; n < 2; ++n) {
            const int rr_  = wc * 32 + n * 16 + li;
            const int boff = rr_ * 64 + ((grp * 16) ^ (((rr_ >> 1) & 3) << 4));
            bfr[n] = *(const short8*)((const char*)Bs + boff);
        }
#pragma unroll
        for (int m = 0; m < 4; ++m)
#pragma unroll
            for (int n = 0; n < 2; ++n)
                acc[m][n] = __builtin_amdgcn_mfma_f32_16x16x32_bf16(
                    af[m], bfr[n], acc[m][n], 0, 0, 0);
        __syncthreads();
    }

#pragma unroll
    for (int m = 0; m < 4; ++m) {
        const int growb = m0 + wr * 64 + m * 16 + grp * 4;
#pragma unroll
        for (int n = 0; n < 2; ++n) {
            const int gcol = n0 + wc * 32 + n * 16 + li;
            const float bv = bias[gcol];
#pragma unroll
            for (int j = 0; j < 4; ++j) {
                const int grow = growb + j;
                if (grow >= M) continue;
                float val = fmaxf(acc[m][n][j] + bv, 0.f);
                const size_t oo = (size_t)grow * N + gcol;
                if (out_rb) out_rb[oo] = f2b(val);
                float sum = val;
                if (residf) sum += residf[oo];
                if (out_sf) out_sf[oo] = sum;
                if (out_sb) out_sb[oo] = f2b(sum);
            }
        }
    }
}

// ------------------------------------------------------ weight transpose ----
struct TDesc { const float* src; bf16* dst; int K, N, nblk, nb32; };
struct TPack { TDesc d[28]; int n; };

__global__ __launch_bounds__(256)
void transpose_kernel(TPack p)
{
    __shared__ float t[32][33];
    int b = blockIdx.x, mi = 0;
    while (mi < p.n && b >= p.d[mi].nblk) { b -= p.d[mi].nblk; ++mi; }
    if (mi >= p.n) return;
    TDesc d = p.d[mi];
    const int kb = b / d.nb32, nb = b % d.nb32;
    const int k0 = kb * 32, n0 = nb * 32;
    const int tx = threadIdx.x & 31, ty = threadIdx.x >> 5;
#pragma unroll
    for (int qq = 0; qq < 4; ++qq) {
        const int kk = ty + qq * 8;
        t[kk][tx] = d.src[(size_t)(k0 + kk) * d.N + n0 + tx];
    }
    __syncthreads();
#pragma unroll
    for (int qq = 0; qq < 4; ++qq) {
        const int nn = ty + qq * 8;
        d.dst[(size_t)(n0 + nn) * d.K + k0 + tx] = f2b(t[tx][nn]);
    }
}

// ---------------------------------------------------------------- CSR build
__global__ void deg_kernel(const int* __restrict__ idx, int n, int* deg)
{
    int e = blockIdx.x * 256 + threadIdx.x;
    if (e < n) atomicAdd(&deg[idx[e]], 1);
}

__global__ __launch_bounds__(256)
void scan_kernel(const int* __restrict__ deg, int* __restrict__ offs, int n)
{
    __shared__ int tot[256];
    const int t = threadIdx.x;
    const int per = (n + 255) / 256;
    const int b = t * per;
    int s = 0;
    for (int i = 0; i < per; ++i) if (b + i < n) s += deg[b + i];
    tot[t] = s;
    __syncthreads();
    for (int d = 1; d < 256; d <<= 1) {
        int v = (t >= d) ? tot[t - d] : 0;
        __syncthreads();
        tot[t] += v;
        __syncthreads();
    }
    int excl = (t == 0) ? 0 : tot[t - 1];
    for (int i = 0; i < per; ++i)
        if (b + i < n) { offs[b + i] = excl; excl += deg[b + i]; }
    if (t == 255) offs[n] = tot[255];
}

__global__ void perm_kernel(const int* __restrict__ idx, int n,
                            int* cursor, int* __restrict__ perm)
{
    int e = blockIdx.x * 256 + threadIdx.x;
    if (e < n) { int p = atomicAdd(&cursor[idx[e]], 1); perm[p] = e; }
}

// -------------- merged node_in gather (CSR) + edge seg-reduce ---------------
// blocks [0,NN): node_in; blocks [NN, NN+nseg): seg-reduce e1f->ge (64 rows).
__global__ __launch_bounds__(128)
void node_seg_kernel(const bf16* __restrict__ exb, const bf16* __restrict__ e1f,
                     const bf16* __restrict__ usb, const int* __restrict__ nbat,
                     const int* __restrict__ offs_s, const int* __restrict__ perm_s,
                     const int* __restrict__ offs_d, const int* __restrict__ perm_d,
                     bf16* __restrict__ node_in,
                     const int* __restrict__ ebat, float* ge)
{
    const int c = threadIdx.x;
    if ((int)blockIdx.x >= NN) {
        const int r0 = ((int)blockIdx.x - NN) * 64;
        if (r0 >= NE) return;
        const int r1 = min(r0 + 64, NE);
        int g = ebat[r0];
        float s = 0.f;
        for (int r = r0; r < r1; ++r) {
            const int gb = ebat[r];
            if (gb != g) {
                atomicAdd(&ge[(size_t)g * LAT + c], s);
                g = gb; s = 0.f;
            }
            s += b2f(e1f[(size_t)r * LAT + c]);
        }
        atomicAdd(&ge[(size_t)g * LAT + c], s);
        return;
    }
    const int i = blockIdx.x;
    float s1 = 0.f, s2 = 0.f;
    const int s_lo = offs_s[i], s_hi = offs_s[i + 1];
    for (int j = s_lo; j < s_hi; ++j)
        s1 += b2f(e1f[(size_t)perm_s[j] * LAT + c]);
    const int d_lo = offs_d[i], d_hi = offs_d[i + 1];
    for (int j = d_lo; j < d_hi; ++j)
        s2 += b2f(e1f[(size_t)perm_d[j] * LAT + c]);
    const size_t o = (size_t)i * (4 * LAT);
    node_in[o + c]           = exb[(size_t)i * LAT + c];
    node_in[o + LAT + c]     = f2b(s1);
    node_in[o + 2 * LAT + c] = f2b(s2);
    node_in[o + 3 * LAT + c] = usb[(size_t)nbat[i] * LAT + c];
}

// -------------------------------- sorted-batch segmented reduce -------------
__global__ __launch_bounds__(128)
void seg_reduce_kernel(const bf16* __restrict__ vals, const int* __restrict__ batch,
                       float* out, int R, int rows_per_block)
{
    const int r0 = blockIdx.x * rows_per_block;
    if (r0 >= R) return;
    const int c = threadIdx.x;
    const int r1 = min(r0 + rows_per_block, R);
    int g = batch[r0];
    float s = 0.f;
    for (int r = r0; r < r1; ++r) {
        const int gb = batch[r];
        if (gb != g) {
            atomicAdd(&out[(size_t)g * LAT + c], s);
            g = gb; s = 0.f;
        }
        s += b2f(vals[(size_t)r * LAT + c]);
    }
    atomicAdd(&out[(size_t)g * LAT + c], s);
}

// ------------------------------------------------------------ small kernels
__global__ void build_g_in_kernel(const float* __restrict__ us,
                                  const float* __restrict__ gx,
                                  const float* __restrict__ ge,
                                  bf16* __restrict__ out)
{
    int id = blockIdx.x * 256 + threadIdx.x;
    if (id >= NG * 384) return;
    int g = id / 384, c = id % 384;
    int seg = c >> 7, c7 = c & 127;
    float v;
    if (seg == 0)      v = us[g * LAT + c7];
    else if (seg == 1) v = gx[g * LAT + c7];
    else               v = ge[g * LAT + c7];
    out[id] = f2b(v);
}

__global__ void counts_kernel(const int* __restrict__ nbat, float* counts)
{
    int id = blockIdx.x * 256 + threadIdx.x;
    if (id < NN) atomicAdd(&counts[nbat[id]], 1.0f);
}

__global__ void cvt_kernel(const float* __restrict__ in, bf16* __restrict__ out, int n)
{
    int id = blockIdx.x * 256 + threadIdx.x;
    if (id < n) out[id] = f2b(in[id]);
}

__global__ void us_double_kernel(float* us)
{
    int id = blockIdx.x * 256 + threadIdx.x;
    if (id < NG * LAT) us[id] *= 2.0f;
}

__global__ __launch_bounds__(64)
void dec2_kernel(const bf16* __restrict__ dh, const float* __restrict__ W2,
                 const float* __restrict__ b2, const float* __restrict__ lp,
                 const int* __restrict__ nbat, float* __restrict__ ptmp, float* psum)
{
    int i = blockIdx.x;
    int l = threadIdx.x;
    float a0 = 0.f, a1 = 0.f, a2 = 0.f;
#pragma unroll
    for (int q = 0; q < 2; ++q) {
        int k = l + q * 64;
        float h = b2f(dh[i * LAT + k]);
        a0 += h * W2[k * 3 + 0];
        a1 += h * W2[k * 3 + 1];
        a2 += h * W2[k * 3 + 2];
    }
#pragma unroll
    for (int off = 32; off > 0; off >>= 1) {
        a0 += __shfl_down(a0, off, 64);
        a1 += __shfl_down(a1, off, 64);
        a2 += __shfl_down(a2, off, 64);
    }
    if (l == 0) {
        int g = nbat[i];
        float p0 = lp[i*3+0] + a0 + b2[0];
        float p1 = lp[i*3+1] + a1 + b2[1];
        float p2 = lp[i*3+2] + a2 + b2[2];
        ptmp[i*3+0] = p0; ptmp[i*3+1] = p1; ptmp[i*3+2] = p2;
        atomicAdd(&psum[g*3+0], p0);
        atomicAdd(&psum[g*3+1], p1);
        atomicAdd(&psum[g*3+2], p2);
    }
}

__global__ void finalize_pos_kernel(const float* __restrict__ ptmp,
                                    const float* __restrict__ psum,
                                    const float* __restrict__ counts,
                                    const int* __restrict__ nbat,
                                    float* __restrict__ lp, float* __restrict__ pos_out)
{
    int id = blockIdx.x * 256 + threadIdx.x;
    if (id >= NN * 3) return;
    int i = id / 3, d = id % 3;
    int g = nbat[i];
    float v = ptmp[id] - psum[g*3+d] / fmaxf(counts[g], 1.f);
    lp[id] = v;
    pos_out[id] = v;
}

// ----------------------------------------------------------------- launch ----
extern "C" void kernel_launch(void* const* d_in, const int* in_sizes, int n_in,
                              void* d_out, int out_size, void* d_ws, size_t ws_size,
                              hipStream_t stream)
{
    const float* x        = (const float*)d_in[0];
    const int*   ei       = (const int*)d_in[1];
    const int*   src      = ei;
    const int*   dst      = ei + NE;
    const float* eattr    = (const float*)d_in[2];
    const float* u        = (const float*)d_in[3];
    const int*   nbat     = (const int*)d_in[4];
    const int*   ebat     = (const int*)d_in[5];
    const float* lp_init  = (const float*)d_in[7];
    const float* pW1 = (const float*)d_in[8];  const float* pb1 = (const float*)d_in[9];
    const float* pW2 = (const float*)d_in[10]; const float* pb2 = (const float*)d_in[11];
    const float* dW1 = (const float*)d_in[12]; const float* db1 = (const float*)d_in[13];
    const float* dW2 = (const float*)d_in[14]; const float* db2 = (const float*)d_in[15];
    const float* eW1 = (const float*)d_in[16]; const float* eb1 = (const float*)d_in[17];
    const float* eW2 = (const float*)d_in[18]; const float* eb2 = (const float*)d_in[19];
    const float* eW3 = (const float*)d_in[20]; const float* eb3 = (const float*)d_in[21];
    const float* nW1 = (const float*)d_in[22]; const float* nb1 = (const float*)d_in[23];
    const float* nW2 = (const float*)d_in[24]; const float* nb2 = (const float*)d_in[25];
    const float* nW3 = (const float*)d_in[26]; const float* nb3 = (const float*)d_in[27];
    const float* gW1 = (const float*)d_in[28]; const float* gb1 = (const float*)d_in[29];
    const float* gW2 = (const float*)d_in[30]; const float* gb2 = (const float*)d_in[31];
    const float* gW3 = (const float*)d_in[32]; const float* gb3 = (const float*)d_in[33];
    const float* dcW1 = (const float*)d_in[34]; const float* dcb1 = (const float*)d_in[35];
    const float* dcW2 = (const float*)d_in[36]; const float* dcb2 = (const float*)d_in[37];

    float* xs = (float*)d_out;
    float* es = xs + (size_t)NN * LAT;
    float* us = es + (size_t)NE * LAT;
    float* pos_out = us + (size_t)NG * LAT;

    char* wp = (char*)d_ws;
    auto alloc = [&](size_t nbytes) {
        void* r = (void*)wp;
        wp += (nbytes + 255) & ~(size_t)255;
        return r;
    };
    bf16* eW1t = (bf16*)alloc((size_t)3*512*512*2);
    bf16* eW2t = (bf16*)alloc((size_t)3*512*512*2);
    bf16* eW3t = (bf16*)alloc((size_t)3*128*512*2);
    bf16* nW1t = (bf16*)alloc((size_t)3*512*512*2);
    bf16* nW2t = (bf16*)alloc((size_t)3*512*512*2);
    bf16* nW3t = (bf16*)alloc((size_t)3*128*512*2);
    bf16* gW1t = (bf16*)alloc((size_t)2*512*384*2);
    bf16* gW2t = (bf16*)alloc((size_t)2*512*512*2);
    bf16* gW3t = (bf16*)alloc((size_t)2*128*512*2);
    bf16* pW2t = (bf16*)alloc((size_t)128*128*2);
    bf16* dW2t = (bf16*)alloc((size_t)128*128*2);
    bf16* dcW1t = (bf16*)alloc((size_t)128*128*2);
    bf16* exb  = (bf16*)alloc((size_t)NN*LAT*2);
    bf16* usb  = (bf16*)alloc((size_t)NG*LAT*2);
    bf16* esb  = (bf16*)alloc((size_t)NE*LAT*2);
    bf16* eeb  = (bf16*)alloc((size_t)NE*LAT*2);
    bf16* h1   = (bf16*)alloc((size_t)NE*HIDN*2);
    bf16* h2   = (bf16*)alloc((size_t)NE*HIDN*2);
    bf16* e1f  = (bf16*)alloc((size_t)NE*LAT*2);
    bf16* x1f  = (bf16*)alloc((size_t)NN*LAT*2);
    float* gx  = (float*)alloc((size_t)NG*LAT*4);
    float* ge  = (float*)alloc((size_t)NG*LAT*4);
    bf16* node_in = (bf16*)alloc((size_t)NN*HIDN*2);
    bf16* nh1  = (bf16*)alloc((size_t)NN*HIDN*2);
    bf16* nh2  = (bf16*)alloc((size_t)NN*HIDN*2);
    bf16* xsb  = (bf16*)alloc((size_t)NN*LAT*2);
    bf16* g_in = (bf16*)alloc((size_t)NG*384*2);
    bf16* gh1  = (bf16*)alloc((size_t)NG*HIDN*2);
    bf16* gh2  = (bf16*)alloc((size_t)NG*HIDN*2);
    bf16* dh   = (bf16*)alloc((size_t)NN*LAT*2);
    float* lp   = (float*)alloc((size_t)NN*3*4);
    float* ptmp = (float*)alloc((size_t)NN*3*4);
    float* psum = (float*)alloc((size_t)NG*3*4);
    float* counts = (float*)alloc((size_t)NG*4);
    int* deg    = (int*)alloc((size_t)NN*4);
    int* offs_s = (int*)alloc((size_t)(NN+1)*4);
    int* offs_d = (int*)alloc((size_t)(NN+1)*4);
    int* cur_s  = (int*)alloc((size_t)NN*4);
    int* cur_d  = (int*)alloc((size_t)NN*4);
    int* perm_s = (int*)alloc((size_t)NE*4);
    int* perm_d = (int*)alloc((size_t)NE*4);

    hipMemcpyAsync(xs, x,     (size_t)NN*LAT*4, hipMemcpyDeviceToDevice, stream);
    hipMemcpyAsync(us, u,     (size_t)NG*LAT*4, hipMemcpyDeviceToDevice, stream);
    hipMemcpyAsync(lp, lp_init, (size_t)NN*3*4, hipMemcpyDeviceToDevice, stream);
    hipMemsetAsync(counts, 0, NG*4, stream);
    counts_kernel<<<(NN+255)/256, 256, 0, stream>>>(nbat, counts);
    cvt_kernel<<<(NG*LAT+255)/256, 256, 0, stream>>>(us, usb, NG*LAT);
    cvt_kernel<<<(NE*LAT+255)/256, 256, 0, stream>>>(eattr, esb, NE*LAT);

    const int eb256 = (NE + 255) / 256;
    hipMemsetAsync(deg, 0, NN*4, stream);
    deg_kernel<<<eb256, 256, 0, stream>>>(src, NE, deg);
    scan_kernel<<<1, 256, 0, stream>>>(deg, offs_s, NN);
    hipMemsetAsync(deg, 0, NN*4, stream);
    deg_kernel<<<eb256, 256, 0, stream>>>(dst, NE, deg);
    scan_kernel<<<1, 256, 0, stream>>>(deg, offs_d, NN);
    hipMemcpyAsync(cur_s, offs_s, NN*4, hipMemcpyDeviceToDevice, stream);
    hipMemcpyAsync(cur_d, offs_d, NN*4, hipMemcpyDeviceToDevice, stream);
    perm_kernel<<<eb256, 256, 0, stream>>>(src, NE, cur_s, perm_s);
    perm_kernel<<<eb256, 256, 0, stream>>>(dst, NE, cur_d, perm_d);

    TPack pk{}; int nd = 0, totb = 0;
    auto addT = [&](const float* s, bf16* d, int K, int N) {
        pk.d[nd].src = s; pk.d[nd].dst = d; pk.d[nd].K = K; pk.d[nd].N = N;
        pk.d[nd].nblk = (K/32)*(N/32); pk.d[nd].nb32 = N/32;
        totb += pk.d[nd].nblk; ++nd;
    };
    for (int l = 0; l < 3; ++l) {
        addT(eW1 + (size_t)l*512*512, eW1t + (size_t)l*512*512, 512, 512);
        addT(eW2 + (size_t)l*512*512, eW2t + (size_t)l*512*512, 512, 512);
        addT(eW3 + (size_t)l*512*128, eW3t + (size_t)l*128*512, 512, 128);
        addT(nW1 + (size_t)l*512*512, nW1t + (size_t)l*512*512, 512, 512);
        addT(nW2 + (size_t)l*512*512, nW2t + (size_t)l*512*512, 512, 512);
        addT(nW3 + (size_t)l*512*128, nW3t + (size_t)l*128*512, 512, 128);
    }
    for (int l = 0; l < 2; ++l) {
        addT(gW1 + (size_t)l*384*512, gW1t + (size_t)l*512*384, 384, 512);
        addT(gW2 + (size_t)l*512*512, gW2t + (size_t)l*512*512, 512, 512);
        addT(gW3 + (size_t)l*512*128, gW3t + (size_t)l*128*512, 512, 128);
    }
    addT(pW2, pW2t, 128, 128);
    addT(dW2, dW2t, 128, 128);
    addT(dcW1, dcW1t, 128, 128);
    pk.n = nd;
    transpose_kernel<<<totb, 256, 0, stream>>>(pk);

    const int mtE  = NE / 128;             // 625
    const int mtN  = (NN + 127) / 128;     // 40
    #define NIL3 nullptr, nullptr, nullptr

    for (int l = 0; l < 3; ++l) {
        // merged POSA (exb) + DISA (eeb)
        posdis_kernel<<<mtN*2 + mtE*2, 256, 0, stream>>>(
            mtN*2, lp, src, dst,
            pW2t, pb2, pW1, pb1, xs, exb,
            dW2t, db2, dW1, db1, esb, eeb);
        // edge MLP layer 1 (gathered concat input), 128x64 tile
        gemm64_kernel<1><<<mtE*8, 256, 0, stream>>>(
            nullptr, eW1t + (size_t)l*512*512, eb1 + l*HIDN, nullptr, nullptr,
            nullptr, nullptr, h1, NE, HIDN, 8,
            src, dst, ebat, exb, eeb, usb);
        // edge MLP layer 2
        gemm64_kernel<0><<<mtE*8, 256, 0, stream>>>(
            h1, eW2t + (size_t)l*512*512, eb2 + l*HIDN, nullptr, nullptr,
            nullptr, nullptr, h2, NE, HIDN, 8, NIL3, NIL3);
        // edge MLP layer 3: e1 (bf16) ; esb += e1 ; es f32 at last layer
        gemm64_kernel<0><<<mtE*2, 256, 0, stream>>>(
            h2, eW3t + (size_t)l*128*512, eb3 + l*LAT, nullptr, esb,
            (l == 2 ? es : nullptr), (l < 2 ? esb : nullptr), e1f, NE, LAT, 2,
            NIL3, NIL3);
        if (l < 2)
            hipMemsetAsync(gx, 0, (size_t)2*NG*LAT*4, stream);
        // merged node_in gather + edge seg-reduce (ge)
        node_seg_kernel<<<NN + (l < 2 ? (NE+63)/64 : 0), 128, 0, stream>>>(
            exb, e1f, usb, nbat, offs_s, perm_s, offs_d, perm_d, node_in,
            ebat, ge);
        gemm64_kernel<0><<<mtN*8, 256, 0, stream>>>(
            node_in, nW1t + (size_t)l*512*512, nb1 + l*HIDN, nullptr, nullptr,
            nullptr, nullptr, nh1, NN, HIDN, 8, NIL3, NIL3);
        gemm64_kernel<0><<<mtN*8, 256, 0, stream>>>(
            nh1, nW2t + (size_t)l*512*512, nb2 + l*HIDN, nullptr, nullptr,
            nullptr, nullptr, nh2, NN, HIDN, 8, NIL3, NIL3);
        gemm64_kernel<0><<<mtN*2, 256, 0, stream>>>(
            nh2, nW3t + (size_t)l*128*512, nb3 + l*LAT, xs, nullptr,
            xs, xsb, x1f, NN, LAT, 2, NIL3, NIL3);
        if (l < 2) {
            seg_reduce_kernel<<<(NN+31)/32, 128, 0, stream>>>(x1f, nbat, gx, NN, 32);
            build_g_in_kernel<<<(NG*384+255)/256, 256, 0, stream>>>(us, gx, ge, g_in);
            gemm_kernel<384><<<8, 256, 0, stream>>>(
                g_in, gW1t + (size_t)l*512*384, gb1 + l*HIDN, nullptr,
                nullptr, nullptr, gh1, NG, HIDN, 8);
            gemm_kernel<512><<<8, 256, 0, stream>>>(
                gh1, gW2t + (size_t)l*512*512, gb2 + l*HIDN, nullptr,
                nullptr, nullptr, gh2, NG, HIDN, 8);
            gemm_kernel<512><<<2, 256, 0, stream>>>(
                gh2, gW3t + (size_t)l*128*512, gb3 + l*LAT, us,
                us, usb, nullptr, NG, LAT, 2);
        } else {
            us_double_kernel<<<(NG*LAT+255)/256, 256, 0, stream>>>(us);
        }
        gemm_kernel<128><<<mtN*2, 256, 0, stream>>>(
            xsb, dcW1t, dcb1, nullptr, nullptr, nullptr, dh, NN, LAT, 2);
        hipMemsetAsync(psum, 0, NG*3*4, stream);
        dec2_kernel<<<NN, 64, 0, stream>>>(dh, dcW2, dcb2, lp, nbat, ptmp, psum);
        finalize_pos_kernel<<<(NN*3+255)/256, 256, 0, stream>>>(
            ptmp, psum, counts, nbat, lp, pos_out + (size_t)l*NN*3);
    }
    (void)in_sizes; (void)n_in; (void)out_size; (void)ws_size;
}